// Round 6
// baseline (245.680 us; speedup 1.0000x reference)
//
#include <hip/hip_runtime.h>
#include <hip/hip_bf16.h>
#include <stdint.h>

typedef __attribute__((ext_vector_type(8))) short short8;
typedef __attribute__((ext_vector_type(4))) float f32x4;
typedef __attribute__((ext_vector_type(16))) float f32x16;
typedef __attribute__((ext_vector_type(4))) unsigned short ushort4v;
typedef __attribute__((ext_vector_type(4))) unsigned int uint4v;

#define TT 2048
#define HH 16
#define CCdim 1024
#define BT 4096   // B*T
#define LOG2E 1.44269504088896f

// round-to-nearest-even f32 -> bf16 (matches jnp astype)
__device__ inline unsigned short f2bf(float f) {
  unsigned u = __float_as_uint(f);
  u += 0x7FFF + ((u >> 16) & 1);
  return (unsigned short)(u >> 16);
}
__device__ inline float bf2f(unsigned short s) {
  return __uint_as_float(((unsigned)s) << 16);
}
__device__ inline unsigned pack2(float a, float b) {
  return (unsigned)f2bf(a) | ((unsigned)f2bf(b) << 16);
}
// HW packed f32->bf16 (RNE), one VALU op for two values
__device__ inline unsigned cvtpk(float lo, float hi) {
  unsigned r;
  asm("v_cvt_pk_bf16_f32 %0, %1, %2" : "=v"(r) : "v"(lo), "v"(hi));
  return r;
}
// swap a's high 32 lanes with b's low 32 lanes (one VALU op).
// NOTE: only safe when a and b are guaranteed-distinct values (else the
// compiler may alias their registers and the swap degenerates) — R4 bug.
__device__ inline void plswap(unsigned &a, unsigned &b) {
  asm("v_permlane32_swap_b32 %0, %1" : "+v"(a), "+v"(b));
}
__device__ inline float fm3(float a, float b, float c) { return fmaxf(fmaxf(a, b), c); }

__device__ inline void gload16(const unsigned short* g, unsigned short* l) {
  __builtin_amdgcn_global_load_lds((const __attribute__((address_space(1))) void*)g,
                                   (__attribute__((address_space(3))) void*)l, 16, 0, 0);
}

// ---------------- prep: casts + bf16-rounded rope table ----------------
__global__ __launch_bounds__(256) void prep(const float* __restrict__ x, const float* __restrict__ wq,
                     const float* __restrict__ wk, const float* __restrict__ wv,
                     const float* __restrict__ wp, unsigned short* __restrict__ xb,
                     unsigned short* __restrict__ wqkv, unsigned short* __restrict__ wpb,
                     float2* __restrict__ tab) {
  long idx = (long)blockIdx.x * blockDim.x + threadIdx.x;
  const long NX = (long)BT * CCdim;        // 4194304
  const long NW = (long)CCdim * CCdim;     // 1048576
  if (idx < NX) { xb[idx] = f2bf(x[idx]); return; }
  idx -= NX;
  if (idx < NW) { wqkv[idx] = f2bf(wq[idx]); return; }
  idx -= NW;
  if (idx < NW) { wqkv[NW + idx] = f2bf(wk[idx]); return; }
  idx -= NW;
  if (idx < NW) { wqkv[2 * NW + idx] = f2bf(wv[idx]); return; }
  idx -= NW;
  if (idx < NW) { wpb[idx] = f2bf(wp[idx]); return; }
  idx -= NW;
  if (idx < (long)TT * 32) {
    int t = (int)(idx >> 5), i = (int)(idx & 31);
    float invf = powf(10000.0f, -(float)i / 32.0f);
    float a = (float)t * invf;
    tab[idx] = make_float2(bf2f(f2bf(cosf(a))), bf2f(f2bf(sinf(a))));
  }
}

// ---------------- GEMM: C[m][n] = sum_k A[m][k] * W[n][k]  (both row-major, K=1024) ----
__global__ __launch_bounds__(256) void gemm_bt(const unsigned short* __restrict__ A,
                                               const unsigned short* __restrict__ W,
                                               float* __restrict__ C, int ldc) {
  __shared__ __align__(16) unsigned short As[128 * 32];
  __shared__ __align__(16) unsigned short Ws[128 * 32];
  const int K = 1024;
  const int tid = threadIdx.x;
  const int lane = tid & 63;
  const int wid = tid >> 6;
  const int wr = wid >> 1, wc = wid & 1;
  const int m0 = blockIdx.y * 128;
  const int n0 = blockIdx.x * 128;

  f32x4 acc[4][4] = {};

  const int srow0 = tid >> 2;
  const int cgrp = tid & 3;
  const int cd = (cgrp ^ ((srow0 >> 1) & 3)) * 8;
  const unsigned short* Arow0 = A + (long)(m0 + srow0) * K + cd;
  const unsigned short* Arow1 = A + (long)(m0 + srow0 + 64) * K + cd;
  const unsigned short* Wrow0 = W + (long)(n0 + srow0) * K + cd;
  const unsigned short* Wrow1 = W + (long)(n0 + srow0 + 64) * K + cd;
  unsigned short* ldsA0 = As + wid * 512;
  unsigned short* ldsA1 = As + 2048 + wid * 512;
  unsigned short* ldsW0 = Ws + wid * 512;
  unsigned short* ldsW1 = Ws + 2048 + wid * 512;

  for (int kt = 0; kt < 32; ++kt) {
    const int kof = kt * 32;
    gload16(Arow0 + kof, ldsA0);
    gload16(Arow1 + kof, ldsA1);
    gload16(Wrow0 + kof, ldsW0);
    gload16(Wrow1 + kof, ldsW1);
    asm volatile("s_waitcnt vmcnt(0)" ::: "memory");
    __syncthreads();
    short8 af[4], bf[4];
#pragma unroll
    for (int mi = 0; mi < 4; ++mi) {
      int r = wr * 64 + mi * 16 + (lane & 15);
      af[mi] = *(const short8*)&As[r * 32 + (((lane >> 4) ^ ((r >> 1) & 3)) * 8)];
    }
#pragma unroll
    for (int nj = 0; nj < 4; ++nj) {
      int r = wc * 64 + nj * 16 + (lane & 15);
      bf[nj] = *(const short8*)&Ws[r * 32 + (((lane >> 4) ^ ((r >> 1) & 3)) * 8)];
    }
#pragma unroll
    for (int mi = 0; mi < 4; ++mi)
#pragma unroll
      for (int nj = 0; nj < 4; ++nj)
        acc[mi][nj] = __builtin_amdgcn_mfma_f32_16x16x32_bf16(af[mi], bf[nj], acc[mi][nj], 0, 0, 0);
    __syncthreads();
  }
#pragma unroll
  for (int mi = 0; mi < 4; ++mi)
#pragma unroll
    for (int nj = 0; nj < 4; ++nj)
#pragma unroll
      for (int j = 0; j < 4; ++j) {
        int rr = m0 + wr * 64 + mi * 16 + 4 * (lane >> 4) + j;
        int ncol = n0 + wc * 64 + nj * 16 + (lane & 15);
        C[(long)rr * ldc + ncol] = acc[mi][nj][j];
      }
}

// ---------------- RMSNorm + RoPE on q,k; write (B,H,T,hd) bf16; fold 1/8 scale into Q ----
__global__ __launch_bounds__(256) void rmsrope(const float* __restrict__ qkv, const float* __restrict__ g,
                                               const float2* __restrict__ tab,
                                               unsigned short* __restrict__ Qh,
                                               unsigned short* __restrict__ Kh) {
  int rid = blockIdx.x * 4 + (threadIdx.x >> 6);  // (b*T + t)*H + h
  int lane = threadIdx.x & 63;
  int h = rid & 15;
  int bt = rid >> 4;
  int t = bt & (TT - 1);
  int b = bt >> 11;
  const float* src = qkv + (long)bt * 3072;
  float2 cs = tab[t * 32 + (lane & 31)];
  float gg = g[lane];
  float sgn = (lane < 32) ? 1.0f : -1.0f;
  long dst = (((long)(b * 16 + h) * TT + t)) * 64 + lane;
#pragma unroll
  for (int qk = 0; qk < 2; ++qk) {
    float u = src[qk * 1024 + h * 64 + lane];
    float ss = u * u;
    ss += __shfl_xor(ss, 1);  ss += __shfl_xor(ss, 2);  ss += __shfl_xor(ss, 4);
    ss += __shfl_xor(ss, 8);  ss += __shfl_xor(ss, 16); ss += __shfl_xor(ss, 32);
    float r = rsqrtf(ss * (1.0f / 64.0f) + 1e-5f);
    float xn = u * r * gg;
    float pr = __shfl_xor(xn, 32);
    float out = xn * cs.x + sgn * pr * cs.y;
    if (qk == 0) Qh[dst] = f2bf(out * 0.125f);
    else         Kh[dst] = f2bf(out);
  }
}

// ---------------- V repack: qkv f32 (cols 2048..3071) -> Vt bf16 (B,H,hd,T) ----------
__global__ __launch_bounds__(256) void vrepack(const float* __restrict__ qkv,
                                               unsigned short* __restrict__ Vt) {
  __shared__ __align__(16) unsigned short S[64][72];
  int blk = blockIdx.x;          // bh*32 + ttile
  int bh = blk >> 5;
  int tt = blk & 31;
  int b = bh >> 4, h = bh & 15;
  int tid = threadIdx.x;
#pragma unroll
  for (int pass = 0; pass < 4; ++pass) {
    int tl = pass * 16 + (tid >> 4);
    int cg = tid & 15;
    float4 v = *(const float4*)&qkv[(long)(b * TT + tt * 64 + tl) * 3072 + 2048 + h * 64 + cg * 4];
    ushort4v o = { f2bf(v.x), f2bf(v.y), f2bf(v.z), f2bf(v.w) };
    *(ushort4v*)&S[tl][cg * 4] = o;
  }
  __syncthreads();
  int d = tid >> 2, ts = tid & 3;
  short8 o0, o1;
#pragma unroll
  for (int t2 = 0; t2 < 8; ++t2) o0[t2] = (short)S[ts * 16 + t2][d];
#pragma unroll
  for (int t2 = 0; t2 < 8; ++t2) o1[t2] = (short)S[ts * 16 + 8 + t2][d];
  unsigned short* dst = Vt + ((long)bh * 64 + d) * TT + tt * 64 + ts * 16;
  *(short8*)dst = o0;
  *(short8*)(dst + 8) = o1;
}

// ---------------- flash attention, KV-split x2: each wave = 32 q-rows x 1024 kv ----
// Swapped QK^T 32x32x16 MFMA, fully in-register softmax, compact (<=128 VGPR) for
// 4 waves/SIMD. Writes unnormalized O (f32) + per-row (m, ell) partials.
__global__ __launch_bounds__(256, 4) void attn(const unsigned short* __restrict__ Qh,
                                               const unsigned short* __restrict__ Kh,
                                               const unsigned short* __restrict__ Vt,
                                               float* __restrict__ Opart,
                                               float2* __restrict__ ML) {
  const int lane = threadIdx.x & 63;
  const int wid = threadIdx.x >> 6;
  int bid = blockIdx.x;
  bid = (bid & 7) * 128 + (bid >> 3);       // XCD swizzle (1024 % 8 == 0: bijective)
  const int w = bid * 4 + wid;              // 0..4095
  const int qt = w & 63;
  const int half = (w >> 6) & 1;
  const int bh = w >> 7;                    // 0..31
  const long bhT = (long)bh * TT;
  const int q0 = qt * 32;
  const int l31 = lane & 31;
  const int hk = (lane >> 5) * 8;           // k-chunk sub-offset

  // Q B-frags: qf[c] = Q[q0+l31][c*16 + hk .. +7]  (Q pre-scaled by 1/8)
  short8 qf[4];
  {
    const unsigned short* qp = Qh + (bhT + q0 + l31) * 64 + hk;
#pragma unroll
    for (int c = 0; c < 4; ++c) qf[c] = *(const short8*)(qp + c * 16);
  }

  const unsigned short* kp = Kh + (bhT + half * 1024 + l31) * 64 + hk;
  const unsigned short* vp0 = Vt + ((long)bh * 64 + l31) * TT + half * 1024 + hk;
  const unsigned short* vp1 = vp0 + (long)32 * TT;

  f32x16 oacc0 = {}, oacc1 = {};
  float m = -1e30f, ell = 0.f;

  short8 kf[4];
#pragma unroll
  for (int c = 0; c < 4; ++c) kf[c] = *(const short8*)(kp + c * 16);

  for (int t = 0; t < 32; ++t) {
    // V loads for this tile: in flight during QK + softmax (~500 cyc)
    short8 vf0[2], vf1[2];
#pragma unroll
    for (int c = 0; c < 2; ++c) {
      vf0[c] = *(const short8*)(vp0 + t * 32 + c * 16);
      vf1[c] = *(const short8*)(vp1 + t * 32 + c * 16);
    }
    // S^T[k][q]: lane q=l31, k=(reg&3)+8*(reg>>2)+4*(lane>>5)
    __builtin_amdgcn_s_setprio(1);
    f32x16 s = {};
#pragma unroll
    for (int c = 0; c < 4; ++c)
      s = __builtin_amdgcn_mfma_f32_32x32x16_bf16(kf[c], qf[c], s, 0, 0, 0);
    __builtin_amdgcn_s_setprio(0);
    // K prefetch for next tile
    {
      int tn = (t < 31) ? (t + 1) : 31;
      const unsigned short* kpn = kp + tn * 2048;
#pragma unroll
      for (int c = 0; c < 4; ++c) kf[c] = *(const short8*)(kpn + c * 16);
    }

    // ---- softmax, fully per-lane for one q-row ----
    float y0 = fm3(s[0], s[1], s[2]),   y1 = fm3(s[3], s[4], s[5]);
    float y2 = fm3(s[6], s[7], s[8]),   y3 = fm3(s[9], s[10], s[11]);
    float y4 = fm3(s[12], s[13], s[14]);
    float mx = fmaxf(fm3(y0, y1, y2), fm3(y3, y4, s[15]));
    mx = fmaxf(mx, __shfl_xor(mx, 32));   // cross-half combine (R2-validated path)
    if (!__all(mx <= m + 8.0f)) {           // defer-max
      float mn = fmaxf(m, mx);
      float corr = __expf(m - mn);
      m = mn;
      ell *= corr;
#pragma unroll
      for (int r = 0; r < 16; ++r) { oacc0[r] *= corr; oacc1[r] *= corr; }
    }
    float nml = -m * LOG2E;
#pragma unroll
    for (int r = 0; r < 16; ++r) s[r] = exp2f(fmaf(s[r], LOG2E, nml));
    float t0 = s[0] + s[1], t1 = s[2] + s[3], t2s = s[4] + s[5], t3 = s[6] + s[7];
    float t4 = s[8] + s[9], t5 = s[10] + s[11], t6 = s[12] + s[13], t7 = s[14] + s[15];
    t0 += t1; t2s += t3; t4 += t5; t6 += t7;
    ell += (t0 + t2s) + (t4 + t6);

    // pack P^T pairs and swap halves (operands always distinct values here)
    unsigned a0 = cvtpk(s[0], s[1]),   a1 = cvtpk(s[2], s[3]);
    unsigned a2 = cvtpk(s[4], s[5]),   a3 = cvtpk(s[6], s[7]);
    unsigned a4 = cvtpk(s[8], s[9]),   a5 = cvtpk(s[10], s[11]);
    unsigned a6 = cvtpk(s[12], s[13]), a7 = cvtpk(s[14], s[15]);
    plswap(a0, a2); plswap(a1, a3); plswap(a4, a6); plswap(a5, a7);
    uint4v f0 = { a0, a1, a2, a3 };
    uint4v f1 = { a4, a5, a6, a7 };
    short8 pf0 = __builtin_bit_cast(short8, f0);
    short8 pf1 = __builtin_bit_cast(short8, f1);

    // O^T[d][q] += V^T[d][k] P^T[k][q]
    __builtin_amdgcn_s_setprio(1);
    oacc0 = __builtin_amdgcn_mfma_f32_32x32x16_bf16(vf0[0], pf0, oacc0, 0, 0, 0);
    oacc0 = __builtin_amdgcn_mfma_f32_32x32x16_bf16(vf0[1], pf1, oacc0, 0, 0, 0);
    oacc1 = __builtin_amdgcn_mfma_f32_32x32x16_bf16(vf1[0], pf0, oacc1, 0, 0, 0);
    oacc1 = __builtin_amdgcn_mfma_f32_32x32x16_bf16(vf1[1], pf1, oacc1, 0, 0, 0);
    __builtin_amdgcn_s_setprio(0);
  }

  float ellf = ell + __shfl_xor(ell, 32);
  const long prow = (long)(half * 32 + bh) * TT + q0 + l31;
  float* orow = Opart + prow * 64;
  const int dhalf = 4 * (lane >> 5);
#pragma unroll
  for (int i = 0; i < 8; ++i) {
    int d = (2 * i & 3) + 8 * (i >> 1) + dhalf;
    *(float2*)&orow[d]      = make_float2(oacc0[2 * i], oacc0[2 * i + 1]);
    *(float2*)&orow[32 + d] = make_float2(oacc1[2 * i], oacc1[2 * i + 1]);
  }
  if (lane < 32) ML[prow] = make_float2(m, ellf);
}

// ---------------- combine the two KV-half partials -> Y bf16 ----------------
__global__ __launch_bounds__(256) void combine(const float* __restrict__ Opart,
                                               const float2* __restrict__ ML,
                                               unsigned short* __restrict__ Y) {
  const long HALF = (long)32 * TT * 64;     // 4194304
  int idx = blockIdx.x * 256 + threadIdx.x; // 2M threads: row*32 + dpair
  int row = idx >> 5;                       // 0..65535 = bh*2048 + qrow
  int d = (idx & 31) * 2;
  float2 o0 = *(const float2*)&Opart[(long)row * 64 + d];
  float2 o1 = *(const float2*)&Opart[HALF + (long)row * 64 + d];
  float2 ml0 = ML[row], ml1 = ML[65536 + row];
  float mm = fmaxf(ml0.x, ml1.x);
  float w0 = __expf(ml0.x - mm), w1 = __expf(ml1.x - mm);
  float rinv = 1.0f / (ml0.y * w0 + ml1.y * w1);
  float ox = (o0.x * w0 + o1.x * w1) * rinv;
  float oy = (o0.y * w0 + o1.y * w1) * rinv;
  int bh = row >> 11, qrow = row & (TT - 1);
  int b = bh >> 4, h = bh & 15;
  *(unsigned*)&Y[((long)(b * TT + qrow)) * CCdim + h * 64 + d] = pack2(ox, oy);
}

extern "C" void kernel_launch(void* const* d_in, const int* in_sizes, int n_in,
                              void* d_out, int out_size, void* d_ws, size_t ws_size,
                              hipStream_t stream) {
  const float* x  = (const float*)d_in[0];
  const float* wq = (const float*)d_in[1];
  const float* wk = (const float*)d_in[2];
  const float* wv = (const float*)d_in[3];
  const float* wp = (const float*)d_in[4];
  const float* g  = (const float*)d_in[5];

  char* w = (char*)d_ws;
  unsigned short* xb   = (unsigned short*)w; w += (long)BT * CCdim * 2;
  unsigned short* wqkv = (unsigned short*)w; w += (long)3 * CCdim * CCdim * 2;
  unsigned short* wpb  = (unsigned short*)w; w += (long)CCdim * CCdim * 2;
  float* qkv           = (float*)w;          w += (long)BT * 3 * CCdim * 4;
  unsigned short* qh   = (unsigned short*)w; w += (long)BT * CCdim * 2;
  unsigned short* kh   = (unsigned short*)w; w += (long)BT * CCdim * 2;
  unsigned short* vt   = (unsigned short*)w; w += (long)BT * CCdim * 2;
  unsigned short* yb   = (unsigned short*)w; w += (long)BT * CCdim * 2;
  float2* tab          = (float2*)w;         w += (long)TT * 32 * 8;

  // attn partials reuse the (dead after vrepack) qkv buffer: 33.5MB + 1MB <= 48MB
  float* Opart = qkv;
  float2* ML   = (float2*)(qkv + 8388608);

  long total = (long)BT * CCdim + 4L * CCdim * CCdim + (long)TT * 32;
  int pblocks = (int)((total + 255) / 256);
  prep<<<pblocks, 256, 0, stream>>>(x, wq, wk, wv, wp, xb, wqkv, wpb, tab);
  gemm_bt<<<dim3(24, 32), 256, 0, stream>>>(xb, wqkv, qkv, 3072);
  rmsrope<<<16384, 256, 0, stream>>>(qkv, g, tab, qh, kh);
  vrepack<<<1024, 256, 0, stream>>>(qkv, vt);
  attn<<<1024, 256, 0, stream>>>(qh, kh, vt, Opart, ML);
  combine<<<8192, 256, 0, stream>>>(Opart, ML, yb);
  gemm_bt<<<dim3(8, 32), 256, 0, stream>>>(yb, wpb, (float*)d_out, 1024);
}

// Round 8
// 186.551 us; speedup vs baseline: 1.3170x; 1.3170x over previous
//
#include <hip/hip_runtime.h>
#include <hip/hip_bf16.h>
#include <stdint.h>

typedef __attribute__((ext_vector_type(8))) short short8;
typedef __attribute__((ext_vector_type(4))) float f32x4;
typedef __attribute__((ext_vector_type(16))) float f32x16;
typedef __attribute__((ext_vector_type(4))) unsigned short ushort4v;
typedef __attribute__((ext_vector_type(4))) unsigned int uint4v;

#define TT 2048
#define HH 16
#define CCdim 1024
#define BT 4096   // B*T
#define LOG2E 1.44269504088896f

// round-to-nearest-even f32 -> bf16 (matches jnp astype)
__device__ inline unsigned short f2bf(float f) {
  unsigned u = __float_as_uint(f);
  u += 0x7FFF + ((u >> 16) & 1);
  return (unsigned short)(u >> 16);
}
__device__ inline float bf2f(unsigned short s) {
  return __uint_as_float(((unsigned)s) << 16);
}
__device__ inline unsigned pack2(float a, float b) {
  return (unsigned)f2bf(a) | ((unsigned)f2bf(b) << 16);
}
// HW packed f32->bf16 (RNE), one VALU op for two values
__device__ inline unsigned cvtpk(float lo, float hi) {
  unsigned r;
  asm("v_cvt_pk_bf16_f32 %0, %1, %2" : "=v"(r) : "v"(lo), "v"(hi));
  return r;
}
// swap a's high 32 lanes with b's low 32 lanes (one VALU op).
// Only safe when a and b are guaranteed-distinct values (R4 bug: compiler
// may alias registers of equal values and the swap degenerates).
__device__ inline void plswap(unsigned &a, unsigned &b) {
  asm("v_permlane32_swap_b32 %0, %1" : "+v"(a), "+v"(b));
}
__device__ inline float fm3(float a, float b, float c) { return fmaxf(fmaxf(a, b), c); }

__device__ inline void gload16(const unsigned short* g, unsigned short* l) {
  __builtin_amdgcn_global_load_lds((const __attribute__((address_space(1))) void*)g,
                                   (__attribute__((address_space(3))) void*)l, 16, 0, 0);
}

// ---------------- prep: casts + bf16-rounded rope table ----------------
__global__ __launch_bounds__(256) void prep(const float* __restrict__ x, const float* __restrict__ wq,
                     const float* __restrict__ wk, const float* __restrict__ wv,
                     const float* __restrict__ wp, unsigned short* __restrict__ xb,
                     unsigned short* __restrict__ wqkv, unsigned short* __restrict__ wpb,
                     float2* __restrict__ tab) {
  long idx = (long)blockIdx.x * blockDim.x + threadIdx.x;
  const long NX = (long)BT * CCdim;        // 4194304
  const long NW = (long)CCdim * CCdim;     // 1048576
  if (idx < NX) { xb[idx] = f2bf(x[idx]); return; }
  idx -= NX;
  if (idx < NW) { wqkv[idx] = f2bf(wq[idx]); return; }
  idx -= NW;
  if (idx < NW) { wqkv[NW + idx] = f2bf(wk[idx]); return; }
  idx -= NW;
  if (idx < NW) { wqkv[2 * NW + idx] = f2bf(wv[idx]); return; }
  idx -= NW;
  if (idx < NW) { wpb[idx] = f2bf(wp[idx]); return; }
  idx -= NW;
  if (idx < (long)TT * 32) {
    int t = (int)(idx >> 5), i = (int)(idx & 31);
    float invf = powf(10000.0f, -(float)i / 32.0f);
    float a = (float)t * invf;
    tab[idx] = make_float2(bf2f(f2bf(cosf(a))), bf2f(f2bf(sinf(a))));
  }
}

// ---------------- GEMM: C[m][n] = sum_k A[m][k] * W[n][k]  (both row-major, K=1024) ----
__global__ __launch_bounds__(256) void gemm_bt(const unsigned short* __restrict__ A,
                                               const unsigned short* __restrict__ W,
                                               float* __restrict__ C, int ldc) {
  __shared__ __align__(16) unsigned short As[128 * 32];
  __shared__ __align__(16) unsigned short Ws[128 * 32];
  const int K = 1024;
  const int tid = threadIdx.x;
  const int lane = tid & 63;
  const int wid = tid >> 6;
  const int wr = wid >> 1, wc = wid & 1;
  const int m0 = blockIdx.y * 128;
  const int n0 = blockIdx.x * 128;

  f32x4 acc[4][4] = {};

  const int srow0 = tid >> 2;
  const int cgrp = tid & 3;
  const int cd = (cgrp ^ ((srow0 >> 1) & 3)) * 8;
  const unsigned short* Arow0 = A + (long)(m0 + srow0) * K + cd;
  const unsigned short* Arow1 = A + (long)(m0 + srow0 + 64) * K + cd;
  const unsigned short* Wrow0 = W + (long)(n0 + srow0) * K + cd;
  const unsigned short* Wrow1 = W + (long)(n0 + srow0 + 64) * K + cd;
  unsigned short* ldsA0 = As + wid * 512;
  unsigned short* ldsA1 = As + 2048 + wid * 512;
  unsigned short* ldsW0 = Ws + wid * 512;
  unsigned short* ldsW1 = Ws + 2048 + wid * 512;

  for (int kt = 0; kt < 32; ++kt) {
    const int kof = kt * 32;
    gload16(Arow0 + kof, ldsA0);
    gload16(Arow1 + kof, ldsA1);
    gload16(Wrow0 + kof, ldsW0);
    gload16(Wrow1 + kof, ldsW1);
    asm volatile("s_waitcnt vmcnt(0)" ::: "memory");
    __syncthreads();
    short8 af[4], bf[4];
#pragma unroll
    for (int mi = 0; mi < 4; ++mi) {
      int r = wr * 64 + mi * 16 + (lane & 15);
      af[mi] = *(const short8*)&As[r * 32 + (((lane >> 4) ^ ((r >> 1) & 3)) * 8)];
    }
#pragma unroll
    for (int nj = 0; nj < 4; ++nj) {
      int r = wc * 64 + nj * 16 + (lane & 15);
      bf[nj] = *(const short8*)&Ws[r * 32 + (((lane >> 4) ^ ((r >> 1) & 3)) * 8)];
    }
#pragma unroll
    for (int mi = 0; mi < 4; ++mi)
#pragma unroll
      for (int nj = 0; nj < 4; ++nj)
        acc[mi][nj] = __builtin_amdgcn_mfma_f32_16x16x32_bf16(af[mi], bf[nj], acc[mi][nj], 0, 0, 0);
    __syncthreads();
  }
#pragma unroll
  for (int mi = 0; mi < 4; ++mi)
#pragma unroll
    for (int nj = 0; nj < 4; ++nj)
#pragma unroll
      for (int j = 0; j < 4; ++j) {
        int rr = m0 + wr * 64 + mi * 16 + 4 * (lane >> 4) + j;
        int ncol = n0 + wc * 64 + nj * 16 + (lane & 15);
        C[(long)rr * ldc + ncol] = acc[mi][nj][j];
      }
}

// ---------------- RMSNorm + RoPE on q,k; Q -> (B,H,T,hd); K -> fragment-packed ----
// Kp layout: [bh][tile(64)][c(4)][lane(64)][8]; value at (bh,tile,c,l,j) =
//   K[bh][tile*32 + (l&31)][c*16 + (l>>5)*8 + j]   (lane-contiguous attn loads)
__global__ __launch_bounds__(256) void rmsrope(const float* __restrict__ qkv, const float* __restrict__ g,
                                               const float2* __restrict__ tab,
                                               unsigned short* __restrict__ Qh,
                                               unsigned short* __restrict__ Kp) {
  int rid = blockIdx.x * 4 + (threadIdx.x >> 6);  // (b*T + t)*H + h
  int lane = threadIdx.x & 63;
  int h = rid & 15;
  int bt = rid >> 4;
  int t = bt & (TT - 1);
  int b = bt >> 11;
  const float* src = qkv + (long)bt * 3072;
  float2 cs = tab[t * 32 + (lane & 31)];
  float gg = g[lane];
  float sgn = (lane < 32) ? 1.0f : -1.0f;
  int bh = b * 16 + h;
  long qdst = ((long)bh * TT + t) * 64 + lane;
  // packed K dest for this (row=t, col=lane)
  long kdst = (((long)bh * 64 + (t >> 5)) * 4 + (lane >> 4)) * 512
            + ((t & 31) + 32 * ((lane >> 3) & 1)) * 8 + (lane & 7);
#pragma unroll
  for (int qk = 0; qk < 2; ++qk) {
    float u = src[qk * 1024 + h * 64 + lane];
    float ss = u * u;
    ss += __shfl_xor(ss, 1);  ss += __shfl_xor(ss, 2);  ss += __shfl_xor(ss, 4);
    ss += __shfl_xor(ss, 8);  ss += __shfl_xor(ss, 16); ss += __shfl_xor(ss, 32);
    float r = rsqrtf(ss * (1.0f / 64.0f) + 1e-5f);
    float xn = u * r * gg;
    float pr = __shfl_xor(xn, 32);
    float out = xn * cs.x + sgn * pr * cs.y;
    if (qk == 0) Qh[qdst] = f2bf(out * 0.125f);
    else         Kp[kdst] = f2bf(out);
  }
}

// ---------------- V repack: qkv f32 -> fragment-packed Vp ----------
// Vp layout: [bh][tile(64)][side(2)][c(2)][lane(64)][8]; value =
//   V[bh][tile*32 + c*16 + (l>>5)*8 + j][side*32 + (l&31)]
__global__ __launch_bounds__(256) void vrepack(const float* __restrict__ qkv,
                                               unsigned short* __restrict__ Vp) {
  __shared__ __align__(16) unsigned short S[64][72];
  int blk = blockIdx.x;          // bh*32 + tt64
  int bh = blk >> 5;
  int tt64 = blk & 31;
  int b = bh >> 4, h = bh & 15;
  int tid = threadIdx.x;
#pragma unroll
  for (int pass = 0; pass < 4; ++pass) {
    int tl = pass * 16 + (tid >> 4);
    int cg = tid & 15;
    float4 v = *(const float4*)&qkv[(long)(b * TT + tt64 * 64 + tl) * 3072 + 2048 + h * 64 + cg * 4];
    ushort4v o = { f2bf(v.x), f2bf(v.y), f2bf(v.z), f2bf(v.w) };
    *(ushort4v*)&S[tl][cg * 4] = o;
  }
  __syncthreads();
  // emit 512 short8 chunks: id = [ttloc(1)|side(1)|c(1)|lane(6)]
  unsigned short* base = Vp + ((long)bh * 64 + tt64 * 2) * 2048;
#pragma unroll
  for (int part = 0; part < 2; ++part) {
    int id = part * 256 + tid;
    int l = id & 63;
    int c = (id >> 6) & 1;
    int s = (id >> 7) & 1;
    int ttloc = (id >> 8) & 1;
    int d = s * 32 + (l & 31);
    int t0 = ttloc * 32 + c * 16 + (l >> 5) * 8;
    short8 o;
#pragma unroll
    for (int j = 0; j < 8; ++j) o[j] = (short)S[t0 + j][d];
    *(short8*)(base + (long)id * 8) = o;
  }
}

// ---------------- flash attention, KV-split x2, fragment-packed K/V ----
// All K/V fragment loads are lane-contiguous 1KB transactions.
__global__ __launch_bounds__(256, 4) void attn(const unsigned short* __restrict__ Qh,
                                               const unsigned short* __restrict__ Kp,
                                               const unsigned short* __restrict__ Vp,
                                               float* __restrict__ Opart,
                                               float2* __restrict__ ML) {
  const int lane = threadIdx.x & 63;
  const int wid = threadIdx.x >> 6;
  int bid = blockIdx.x;
  bid = (bid & 7) * 128 + (bid >> 3);       // XCD swizzle (1024 % 8 == 0: bijective)
  const int w = bid * 4 + wid;              // 0..4095
  const int qt = w & 63;
  const int half = (w >> 6) & 1;
  const int bh = w >> 7;                    // 0..31
  const long bhT = (long)bh * TT;
  const int q0 = qt * 32;
  const int l31 = lane & 31;
  const int hk = (lane >> 5) * 8;

  // Q B-frags (scattered load, once per wave): qf[c] = Q[q0+l31][c*16+hk ..+7]
  short8 qf[4];
  {
    const unsigned short* qp = Qh + (bhT + q0 + l31) * 64 + hk;
#pragma unroll
    for (int c = 0; c < 4; ++c) qf[c] = *(const short8*)(qp + c * 16);
  }

  const unsigned short* kp = Kp + ((long)(bh * 64 + half * 32)) * 2048 + lane * 8;
  const unsigned short* vp = Vp + ((long)(bh * 64 + half * 32)) * 2048 + lane * 8;

  f32x16 oacc0 = {}, oacc1 = {};
  float m = -1e30f, ell = 0.f;

  short8 kf[4];
#pragma unroll
  for (int c = 0; c < 4; ++c) kf[c] = *(const short8*)(kp + c * 512);

  for (int t = 0; t < 32; ++t) {
    // V fragments for this tile (contiguous 1KB loads, consumed after softmax)
    short8 vf0[2], vf1[2];
#pragma unroll
    for (int c = 0; c < 2; ++c) {
      vf0[c] = *(const short8*)(vp + t * 2048 + c * 512);
      vf1[c] = *(const short8*)(vp + t * 2048 + 1024 + c * 512);
    }
    // S^T[k][q]: lane q=l31, k=(reg&3)+8*(reg>>2)+4*(lane>>5)
    __builtin_amdgcn_s_setprio(1);
    f32x16 s = {};
#pragma unroll
    for (int c = 0; c < 4; ++c)
      s = __builtin_amdgcn_mfma_f32_32x32x16_bf16(kf[c], qf[c], s, 0, 0, 0);
    __builtin_amdgcn_s_setprio(0);
    // K prefetch for next tile
    {
      int tn = (t < 31) ? (t + 1) : 31;
      const unsigned short* kpn = kp + tn * 2048;
#pragma unroll
      for (int c = 0; c < 4; ++c) kf[c] = *(const short8*)(kpn + c * 512);
    }

    // ---- softmax, fully per-lane for one q-row ----
    float y0 = fm3(s[0], s[1], s[2]),   y1 = fm3(s[3], s[4], s[5]);
    float y2 = fm3(s[6], s[7], s[8]),   y3 = fm3(s[9], s[10], s[11]);
    float y4 = fm3(s[12], s[13], s[14]);
    float mx = fmaxf(fm3(y0, y1, y2), fm3(y3, y4, s[15]));
    mx = fmaxf(mx, __shfl_xor(mx, 32));   // cross-half combine
    if (!__all(mx <= m + 8.0f)) {           // defer-max
      float mn = fmaxf(m, mx);
      float corr = __expf(m - mn);
      m = mn;
      ell *= corr;
#pragma unroll
      for (int r = 0; r < 16; ++r) { oacc0[r] *= corr; oacc1[r] *= corr; }
    }
    float nml = -m * LOG2E;
#pragma unroll
    for (int r = 0; r < 16; ++r) s[r] = exp2f(fmaf(s[r], LOG2E, nml));
    float t0 = s[0] + s[1], t1 = s[2] + s[3], t2s = s[4] + s[5], t3 = s[6] + s[7];
    float t4 = s[8] + s[9], t5 = s[10] + s[11], t6 = s[12] + s[13], t7 = s[14] + s[15];
    t0 += t1; t2s += t3; t4 += t5; t6 += t7;
    ell += (t0 + t2s) + (t4 + t6);

    // pack P^T pairs and swap halves (operands always distinct values here)
    unsigned a0 = cvtpk(s[0], s[1]),   a1 = cvtpk(s[2], s[3]);
    unsigned a2 = cvtpk(s[4], s[5]),   a3 = cvtpk(s[6], s[7]);
    unsigned a4 = cvtpk(s[8], s[9]),   a5 = cvtpk(s[10], s[11]);
    unsigned a6 = cvtpk(s[12], s[13]), a7 = cvtpk(s[14], s[15]);
    plswap(a0, a2); plswap(a1, a3); plswap(a4, a6); plswap(a5, a7);
    uint4v f0 = { a0, a1, a2, a3 };
    uint4v f1 = { a4, a5, a6, a7 };
    short8 pf0 = __builtin_bit_cast(short8, f0);
    short8 pf1 = __builtin_bit_cast(short8, f1);

    // O^T[d][q] += V^T[d][k] P^T[k][q]
    __builtin_amdgcn_s_setprio(1);
    oacc0 = __builtin_amdgcn_mfma_f32_32x32x16_bf16(vf0[0], pf0, oacc0, 0, 0, 0);
    oacc0 = __builtin_amdgcn_mfma_f32_32x32x16_bf16(vf0[1], pf1, oacc0, 0, 0, 0);
    oacc1 = __builtin_amdgcn_mfma_f32_32x32x16_bf16(vf1[0], pf0, oacc1, 0, 0, 0);
    oacc1 = __builtin_amdgcn_mfma_f32_32x32x16_bf16(vf1[1], pf1, oacc1, 0, 0, 0);
    __builtin_amdgcn_s_setprio(0);
  }

  float ellf = ell + __shfl_xor(ell, 32);
  const long prow = (long)(half * 32 + bh) * TT + q0 + l31;
  float* orow = Opart + prow * 64;
  const int dhalf = 4 * (lane >> 5);
#pragma unroll
  for (int i = 0; i < 8; ++i) {
    int d = (2 * i & 3) + 8 * (i >> 1) + dhalf;
    *(float2*)&orow[d]      = make_float2(oacc0[2 * i], oacc0[2 * i + 1]);
    *(float2*)&orow[32 + d] = make_float2(oacc1[2 * i], oacc1[2 * i + 1]);
  }
  if (lane < 32) ML[prow] = make_float2(m, ellf);
}

// ---------------- combine the two KV-half partials -> Y bf16 ----------------
__global__ __launch_bounds__(256) void combine(const float* __restrict__ Opart,
                                               const float2* __restrict__ ML,
                                               unsigned short* __restrict__ Y) {
  const long HALF = (long)32 * TT * 64;     // 4194304
  int idx = blockIdx.x * 256 + threadIdx.x; // 2M threads: row*32 + dpair
  int row = idx >> 5;                       // 0..65535 = bh*2048 + qrow
  int d = (idx & 31) * 2;
  float2 o0 = *(const float2*)&Opart[(long)row * 64 + d];
  float2 o1 = *(const float2*)&Opart[HALF + (long)row * 64 + d];
  float2 ml0 = ML[row], ml1 = ML[65536 + row];
  float mm = fmaxf(ml0.x, ml1.x);
  float w0 = __expf(ml0.x - mm), w1 = __expf(ml1.x - mm);
  float rinv = 1.0f / (ml0.y * w0 + ml1.y * w1);
  float ox = (o0.x * w0 + o1.x * w1) * rinv;
  float oy = (o0.y * w0 + o1.y * w1) * rinv;
  int bh = row >> 11, qrow = row & (TT - 1);
  int b = bh >> 4, h = bh & 15;
  *(unsigned*)&Y[((long)(b * TT + qrow)) * CCdim + h * 64 + d] = pack2(ox, oy);
}

extern "C" void kernel_launch(void* const* d_in, const int* in_sizes, int n_in,
                              void* d_out, int out_size, void* d_ws, size_t ws_size,
                              hipStream_t stream) {
  const float* x  = (const float*)d_in[0];
  const float* wq = (const float*)d_in[1];
  const float* wk = (const float*)d_in[2];
  const float* wv = (const float*)d_in[3];
  const float* wp = (const float*)d_in[4];
  const float* g  = (const float*)d_in[5];

  char* w = (char*)d_ws;
  unsigned short* xb   = (unsigned short*)w; w += (long)BT * CCdim * 2;
  unsigned short* wqkv = (unsigned short*)w; w += (long)3 * CCdim * CCdim * 2;
  unsigned short* wpb  = (unsigned short*)w; w += (long)CCdim * CCdim * 2;
  float* qkv           = (float*)w;          w += (long)BT * 3 * CCdim * 4;
  unsigned short* qh   = (unsigned short*)w; w += (long)BT * CCdim * 2;
  unsigned short* kp   = (unsigned short*)w; w += (long)BT * CCdim * 2;
  unsigned short* vp   = (unsigned short*)w; w += (long)BT * CCdim * 2;
  unsigned short* yb   = (unsigned short*)w; w += (long)BT * CCdim * 2;
  float2* tab          = (float2*)w;         w += (long)TT * 32 * 8;

  // attn partials reuse the (dead after vrepack) qkv buffer: 33.5MB + 1MB <= 48MB
  float* Opart = qkv;
  float2* ML   = (float2*)(qkv + 8388608);

  long total = (long)BT * CCdim + 4L * CCdim * CCdim + (long)TT * 32;
  int pblocks = (int)((total + 255) / 256);
  prep<<<pblocks, 256, 0, stream>>>(x, wq, wk, wv, wp, xb, wqkv, wpb, tab);
  gemm_bt<<<dim3(24, 32), 256, 0, stream>>>(xb, wqkv, qkv, 3072);
  rmsrope<<<16384, 256, 0, stream>>>(qkv, g, tab, qh, kp);
  vrepack<<<1024, 256, 0, stream>>>(qkv, vp);
  attn<<<1024, 256, 0, stream>>>(qh, kp, vp, Opart, ML);
  combine<<<8192, 256, 0, stream>>>(Opart, ML, yb);
  gemm_bt<<<dim3(8, 32), 256, 0, stream>>>(yb, wpb, (float*)d_out, 1024);
}

// Round 9
// 182.952 us; speedup vs baseline: 1.3429x; 1.0197x over previous
//
#include <hip/hip_runtime.h>
#include <hip/hip_bf16.h>
#include <stdint.h>

typedef __attribute__((ext_vector_type(8))) short short8;
typedef __attribute__((ext_vector_type(4))) float f32x4;
typedef __attribute__((ext_vector_type(16))) float f32x16;
typedef __attribute__((ext_vector_type(4))) unsigned short ushort4v;
typedef __attribute__((ext_vector_type(4))) unsigned int uint4v;

#define TT 2048
#define HH 16
#define CCdim 1024
#define BT 4096   // B*T
#define LOG2E 1.44269504088896f

// round-to-nearest-even f32 -> bf16 (matches jnp astype)
__device__ inline unsigned short f2bf(float f) {
  unsigned u = __float_as_uint(f);
  u += 0x7FFF + ((u >> 16) & 1);
  return (unsigned short)(u >> 16);
}
__device__ inline float bf2f(unsigned short s) {
  return __uint_as_float(((unsigned)s) << 16);
}
__device__ inline unsigned pack2(float a, float b) {
  return (unsigned)f2bf(a) | ((unsigned)f2bf(b) << 16);
}
// HW packed f32->bf16 (RNE), one VALU op for two values
__device__ inline unsigned cvtpk(float lo, float hi) {
  unsigned r;
  asm("v_cvt_pk_bf16_f32 %0, %1, %2" : "=v"(r) : "v"(lo), "v"(hi));
  return r;
}
// swap a's high 32 lanes with b's low 32 lanes (one VALU op).
// Only safe when a and b are guaranteed-distinct values (R4 bug: compiler
// may alias registers of equal values and the swap degenerates).
__device__ inline void plswap(unsigned &a, unsigned &b) {
  asm("v_permlane32_swap_b32 %0, %1" : "+v"(a), "+v"(b));
}

__device__ inline void gload16(const unsigned short* g, unsigned short* l) {
  __builtin_amdgcn_global_load_lds((const __attribute__((address_space(1))) void*)g,
                                   (__attribute__((address_space(3))) void*)l, 16, 0, 0);
}

// ---------------- prep: casts + bf16-rounded rope table ----------------
__global__ __launch_bounds__(256) void prep(const float* __restrict__ x, const float* __restrict__ wq,
                     const float* __restrict__ wk, const float* __restrict__ wv,
                     const float* __restrict__ wp, unsigned short* __restrict__ xb,
                     unsigned short* __restrict__ wqkv, unsigned short* __restrict__ wpb,
                     float2* __restrict__ tab) {
  long idx = (long)blockIdx.x * blockDim.x + threadIdx.x;
  const long NX = (long)BT * CCdim;        // 4194304
  const long NW = (long)CCdim * CCdim;     // 1048576
  if (idx < NX) { xb[idx] = f2bf(x[idx]); return; }
  idx -= NX;
  if (idx < NW) { wqkv[idx] = f2bf(wq[idx]); return; }
  idx -= NW;
  if (idx < NW) { wqkv[NW + idx] = f2bf(wk[idx]); return; }
  idx -= NW;
  if (idx < NW) { wqkv[2 * NW + idx] = f2bf(wv[idx]); return; }
  idx -= NW;
  if (idx < NW) { wpb[idx] = f2bf(wp[idx]); return; }
  idx -= NW;
  if (idx < (long)TT * 32) {
    int t = (int)(idx >> 5), i = (int)(idx & 31);
    float invf = powf(10000.0f, -(float)i / 32.0f);
    float a = (float)t * invf;
    tab[idx] = make_float2(bf2f(f2bf(cosf(a))), bf2f(f2bf(sinf(a))));
  }
}

// ---------------- GEMM: C[m][n] = sum_k A[m][k] * W[n][k]  (both row-major, K=1024) ----
__global__ __launch_bounds__(256) void gemm_bt(const unsigned short* __restrict__ A,
                                               const unsigned short* __restrict__ W,
                                               float* __restrict__ C, int ldc) {
  __shared__ __align__(16) unsigned short As[128 * 32];
  __shared__ __align__(16) unsigned short Ws[128 * 32];
  const int K = 1024;
  const int tid = threadIdx.x;
  const int lane = tid & 63;
  const int wid = tid >> 6;
  const int wr = wid >> 1, wc = wid & 1;
  const int m0 = blockIdx.y * 128;
  const int n0 = blockIdx.x * 128;

  f32x4 acc[4][4] = {};

  const int srow0 = tid >> 2;
  const int cgrp = tid & 3;
  const int cd = (cgrp ^ ((srow0 >> 1) & 3)) * 8;
  const unsigned short* Arow0 = A + (long)(m0 + srow0) * K + cd;
  const unsigned short* Arow1 = A + (long)(m0 + srow0 + 64) * K + cd;
  const unsigned short* Wrow0 = W + (long)(n0 + srow0) * K + cd;
  const unsigned short* Wrow1 = W + (long)(n0 + srow0 + 64) * K + cd;
  unsigned short* ldsA0 = As + wid * 512;
  unsigned short* ldsA1 = As + 2048 + wid * 512;
  unsigned short* ldsW0 = Ws + wid * 512;
  unsigned short* ldsW1 = Ws + 2048 + wid * 512;

  for (int kt = 0; kt < 32; ++kt) {
    const int kof = kt * 32;
    gload16(Arow0 + kof, ldsA0);
    gload16(Arow1 + kof, ldsA1);
    gload16(Wrow0 + kof, ldsW0);
    gload16(Wrow1 + kof, ldsW1);
    asm volatile("s_waitcnt vmcnt(0)" ::: "memory");
    __syncthreads();
    short8 af[4], bf[4];
#pragma unroll
    for (int mi = 0; mi < 4; ++mi) {
      int r = wr * 64 + mi * 16 + (lane & 15);
      af[mi] = *(const short8*)&As[r * 32 + (((lane >> 4) ^ ((r >> 1) & 3)) * 8)];
    }
#pragma unroll
    for (int nj = 0; nj < 4; ++nj) {
      int r = wc * 64 + nj * 16 + (lane & 15);
      bf[nj] = *(const short8*)&Ws[r * 32 + (((lane >> 4) ^ ((r >> 1) & 3)) * 8)];
    }
#pragma unroll
    for (int mi = 0; mi < 4; ++mi)
#pragma unroll
      for (int nj = 0; nj < 4; ++nj)
        acc[mi][nj] = __builtin_amdgcn_mfma_f32_16x16x32_bf16(af[mi], bf[nj], acc[mi][nj], 0, 0, 0);
    __syncthreads();
  }
#pragma unroll
  for (int mi = 0; mi < 4; ++mi)
#pragma unroll
    for (int nj = 0; nj < 4; ++nj)
#pragma unroll
      for (int j = 0; j < 4; ++j) {
        int rr = m0 + wr * 64 + mi * 16 + 4 * (lane >> 4) + j;
        int ncol = n0 + wc * 64 + nj * 16 + (lane & 15);
        C[(long)rr * ldc + ncol] = acc[mi][nj][j];
      }
}

// ---------------- RMSNorm + RoPE on q,k; Q -> (B,H,T,hd); K -> fragment-packed ----
// Kp layout: [bh][tile(64)][c(4)][lane(64)][8]; value at (bh,tile,c,l,j) =
//   K[bh][tile*32 + (l&31)][c*16 + (l>>5)*8 + j]   (lane-contiguous attn loads)
__global__ __launch_bounds__(256) void rmsrope(const float* __restrict__ qkv, const float* __restrict__ g,
                                               const float2* __restrict__ tab,
                                               unsigned short* __restrict__ Qh,
                                               unsigned short* __restrict__ Kp) {
  int rid = blockIdx.x * 4 + (threadIdx.x >> 6);  // (b*T + t)*H + h
  int lane = threadIdx.x & 63;
  int h = rid & 15;
  int bt = rid >> 4;
  int t = bt & (TT - 1);
  int b = bt >> 11;
  const float* src = qkv + (long)bt * 3072;
  float2 cs = tab[t * 32 + (lane & 31)];
  float gg = g[lane];
  float sgn = (lane < 32) ? 1.0f : -1.0f;
  int bh = b * 16 + h;
  long qdst = ((long)bh * TT + t) * 64 + lane;
  // packed K dest for this (row=t, col=lane)
  long kdst = (((long)bh * 64 + (t >> 5)) * 4 + (lane >> 4)) * 512
            + ((t & 31) + 32 * ((lane >> 3) & 1)) * 8 + (lane & 7);
#pragma unroll
  for (int qk = 0; qk < 2; ++qk) {
    float u = src[qk * 1024 + h * 64 + lane];
    float ss = u * u;
    ss += __shfl_xor(ss, 1);  ss += __shfl_xor(ss, 2);  ss += __shfl_xor(ss, 4);
    ss += __shfl_xor(ss, 8);  ss += __shfl_xor(ss, 16); ss += __shfl_xor(ss, 32);
    float r = rsqrtf(ss * (1.0f / 64.0f) + 1e-5f);
    float xn = u * r * gg;
    float pr = __shfl_xor(xn, 32);
    float out = xn * cs.x + sgn * pr * cs.y;
    if (qk == 0) Qh[qdst] = f2bf(out * 0.125f);
    else         Kp[kdst] = f2bf(out);
  }
}

// ---------------- V repack: qkv f32 -> fragment-packed Vp ----------
// Vp layout: [bh][tile(64)][side(2)][c(2)][lane(64)][8]; value =
//   V[bh][tile*32 + c*16 + (l>>5)*8 + j][side*32 + (l&31)]
__global__ __launch_bounds__(256) void vrepack(const float* __restrict__ qkv,
                                               unsigned short* __restrict__ Vp) {
  __shared__ __align__(16) unsigned short S[64][72];
  int blk = blockIdx.x;          // bh*32 + tt64
  int bh = blk >> 5;
  int tt64 = blk & 31;
  int b = bh >> 4, h = bh & 15;
  int tid = threadIdx.x;
#pragma unroll
  for (int pass = 0; pass < 4; ++pass) {
    int tl = pass * 16 + (tid >> 4);
    int cg = tid & 15;
    float4 v = *(const float4*)&qkv[(long)(b * TT + tt64 * 64 + tl) * 3072 + 2048 + h * 64 + cg * 4];
    ushort4v o = { f2bf(v.x), f2bf(v.y), f2bf(v.z), f2bf(v.w) };
    *(ushort4v*)&S[tl][cg * 4] = o;
  }
  __syncthreads();
  // emit 512 short8 chunks: id = [ttloc(1)|side(1)|c(1)|lane(6)]
  unsigned short* base = Vp + ((long)bh * 64 + tt64 * 2) * 2048;
#pragma unroll
  for (int part = 0; part < 2; ++part) {
    int id = part * 256 + tid;
    int l = id & 63;
    int c = (id >> 6) & 1;
    int s = (id >> 7) & 1;
    int ttloc = (id >> 8) & 1;
    int d = s * 32 + (l & 31);
    int t0 = ttloc * 32 + c * 16 + (l >> 5) * 8;
    short8 o;
#pragma unroll
    for (int j = 0; j < 8; ++j) o[j] = (short)S[t0 + j][d];
    *(short8*)(base + (long)id * 8) = o;
  }
}

// ---------------- flash attention, KV-split x2, fragment-packed K/V ----
// FIXED-MAX softmax: |s| = |(q/8)·k| <= ~8.15 by Cauchy-Schwarz (RMS-normed k,
// RoPE isometric), so p = exp(s-8) <= 1.16 is overflow-safe with NO max
// tracking: no max tree, no cross-half shuffle, no __all, no rescale.
__global__ __launch_bounds__(256, 4) void attn(const unsigned short* __restrict__ Qh,
                                               const unsigned short* __restrict__ Kp,
                                               const unsigned short* __restrict__ Vp,
                                               float* __restrict__ Opart,
                                               float* __restrict__ L) {
  const int lane = threadIdx.x & 63;
  const int wid = threadIdx.x >> 6;
  int bid = blockIdx.x;
  bid = (bid & 7) * 128 + (bid >> 3);       // XCD swizzle (1024 % 8 == 0: bijective)
  const int w = bid * 4 + wid;              // 0..4095
  const int qt = w & 63;
  const int half = (w >> 6) & 1;
  const int bh = w >> 7;                    // 0..31
  const long bhT = (long)bh * TT;
  const int q0 = qt * 32;
  const int l31 = lane & 31;
  const int hk = (lane >> 5) * 8;

  // Q B-frags (scattered load, once per wave): qf[c] = Q[q0+l31][c*16+hk ..+7]
  short8 qf[4];
  {
    const unsigned short* qp = Qh + (bhT + q0 + l31) * 64 + hk;
#pragma unroll
    for (int c = 0; c < 4; ++c) qf[c] = *(const short8*)(qp + c * 16);
  }

  const unsigned short* kp = Kp + ((long)(bh * 64 + half * 32)) * 2048 + lane * 8;
  const unsigned short* vp = Vp + ((long)(bh * 64 + half * 32)) * 2048 + lane * 8;

  f32x16 oacc0 = {}, oacc1 = {};
  float ell = 0.f;
  const float NM8 = -8.0f * LOG2E;          // fixed-max shift in exp2 domain

  short8 kf[4];
#pragma unroll
  for (int c = 0; c < 4; ++c) kf[c] = *(const short8*)(kp + c * 512);

  for (int t = 0; t < 32; ++t) {
    // V fragments for this tile (contiguous 1KB loads, consumed after softmax)
    short8 vf0[2], vf1[2];
#pragma unroll
    for (int c = 0; c < 2; ++c) {
      vf0[c] = *(const short8*)(vp + t * 2048 + c * 512);
      vf1[c] = *(const short8*)(vp + t * 2048 + 1024 + c * 512);
    }
    // S^T[k][q]: lane q=l31, k=(reg&3)+8*(reg>>2)+4*(lane>>5)
    __builtin_amdgcn_s_setprio(1);
    f32x16 s = {};
#pragma unroll
    for (int c = 0; c < 4; ++c)
      s = __builtin_amdgcn_mfma_f32_32x32x16_bf16(kf[c], qf[c], s, 0, 0, 0);
    __builtin_amdgcn_s_setprio(0);
    // K prefetch for next tile
    {
      int tn = (t < 31) ? (t + 1) : 31;
      const unsigned short* kpn = kp + tn * 2048;
#pragma unroll
      for (int c = 0; c < 4; ++c) kf[c] = *(const short8*)(kpn + c * 512);
    }

    // ---- fixed-max softmax: p = exp2(s*log2e - 8*log2e), fully per-lane ----
#pragma unroll
    for (int r = 0; r < 16; ++r) s[r] = exp2f(fmaf(s[r], LOG2E, NM8));
    float t0 = s[0] + s[1], t1 = s[2] + s[3], t2s = s[4] + s[5], t3 = s[6] + s[7];
    float t4 = s[8] + s[9], t5 = s[10] + s[11], t6 = s[12] + s[13], t7 = s[14] + s[15];
    t0 += t1; t2s += t3; t4 += t5; t6 += t7;
    ell += (t0 + t2s) + (t4 + t6);

    // pack P^T pairs and swap halves (operands always distinct values here)
    unsigned a0 = cvtpk(s[0], s[1]),   a1 = cvtpk(s[2], s[3]);
    unsigned a2 = cvtpk(s[4], s[5]),   a3 = cvtpk(s[6], s[7]);
    unsigned a4 = cvtpk(s[8], s[9]),   a5 = cvtpk(s[10], s[11]);
    unsigned a6 = cvtpk(s[12], s[13]), a7 = cvtpk(s[14], s[15]);
    plswap(a0, a2); plswap(a1, a3); plswap(a4, a6); plswap(a5, a7);
    uint4v f0 = { a0, a1, a2, a3 };
    uint4v f1 = { a4, a5, a6, a7 };
    short8 pf0 = __builtin_bit_cast(short8, f0);
    short8 pf1 = __builtin_bit_cast(short8, f1);

    // O^T[d][q] += V^T[d][k] P^T[k][q]
    __builtin_amdgcn_s_setprio(1);
    oacc0 = __builtin_amdgcn_mfma_f32_32x32x16_bf16(vf0[0], pf0, oacc0, 0, 0, 0);
    oacc0 = __builtin_amdgcn_mfma_f32_32x32x16_bf16(vf0[1], pf1, oacc0, 0, 0, 0);
    oacc1 = __builtin_amdgcn_mfma_f32_32x32x16_bf16(vf1[0], pf0, oacc1, 0, 0, 0);
    oacc1 = __builtin_amdgcn_mfma_f32_32x32x16_bf16(vf1[1], pf1, oacc1, 0, 0, 0);
    __builtin_amdgcn_s_setprio(0);
  }

  float ellf = ell + __shfl_xor(ell, 32);
  const long prow = (long)(half * 32 + bh) * TT + q0 + l31;
  float* orow = Opart + prow * 64;
  const int dhalf = 4 * (lane >> 5);
#pragma unroll
  for (int i = 0; i < 8; ++i) {
    int d = (2 * i & 3) + 8 * (i >> 1) + dhalf;
    *(float2*)&orow[d]      = make_float2(oacc0[2 * i], oacc0[2 * i + 1]);
    *(float2*)&orow[32 + d] = make_float2(oacc1[2 * i], oacc1[2 * i + 1]);
  }
  if (lane < 32) L[prow] = ellf;
}

// ---------------- combine the two KV-half partials -> Y bf16 ----------------
// Both halves share the same fixed max: O = (O0+O1)/(l0+l1).
__global__ __launch_bounds__(256) void combine(const float* __restrict__ Opart,
                                               const float* __restrict__ L,
                                               unsigned short* __restrict__ Y) {
  const long HALF = (long)32 * TT * 64;     // 4194304
  int idx = blockIdx.x * 256 + threadIdx.x; // 2M threads: row*32 + dpair
  int row = idx >> 5;                       // 0..65535 = bh*2048 + qrow
  int d = (idx & 31) * 2;
  float2 o0 = *(const float2*)&Opart[(long)row * 64 + d];
  float2 o1 = *(const float2*)&Opart[HALF + (long)row * 64 + d];
  float rinv = 1.0f / (L[row] + L[65536 + row]);
  float ox = (o0.x + o1.x) * rinv;
  float oy = (o0.y + o1.y) * rinv;
  int bh = row >> 11, qrow = row & (TT - 1);
  int b = bh >> 4, h = bh & 15;
  *(unsigned*)&Y[((long)(b * TT + qrow)) * CCdim + h * 64 + d] = pack2(ox, oy);
}

extern "C" void kernel_launch(void* const* d_in, const int* in_sizes, int n_in,
                              void* d_out, int out_size, void* d_ws, size_t ws_size,
                              hipStream_t stream) {
  const float* x  = (const float*)d_in[0];
  const float* wq = (const float*)d_in[1];
  const float* wk = (const float*)d_in[2];
  const float* wv = (const float*)d_in[3];
  const float* wp = (const float*)d_in[4];
  const float* g  = (const float*)d_in[5];

  char* w = (char*)d_ws;
  unsigned short* xb   = (unsigned short*)w; w += (long)BT * CCdim * 2;
  unsigned short* wqkv = (unsigned short*)w; w += (long)3 * CCdim * CCdim * 2;
  unsigned short* wpb  = (unsigned short*)w; w += (long)CCdim * CCdim * 2;
  float* qkv           = (float*)w;          w += (long)BT * 3 * CCdim * 4;
  unsigned short* qh   = (unsigned short*)w; w += (long)BT * CCdim * 2;
  unsigned short* kp   = (unsigned short*)w; w += (long)BT * CCdim * 2;
  unsigned short* vp   = (unsigned short*)w; w += (long)BT * CCdim * 2;
  unsigned short* yb   = (unsigned short*)w; w += (long)BT * CCdim * 2;
  float2* tab          = (float2*)w;         w += (long)TT * 32 * 8;

  // attn partials reuse the (dead after vrepack) qkv buffer: 33.5MB + 0.5MB <= 48MB
  float* Opart = qkv;
  float* Lbuf  = qkv + 8388608;

  long total = (long)BT * CCdim + 4L * CCdim * CCdim + (long)TT * 32;
  int pblocks = (int)((total + 255) / 256);
  prep<<<pblocks, 256, 0, stream>>>(x, wq, wk, wv, wp, xb, wqkv, wpb, tab);
  gemm_bt<<<dim3(24, 32), 256, 0, stream>>>(xb, wqkv, qkv, 3072);
  rmsrope<<<16384, 256, 0, stream>>>(qkv, g, tab, qh, kp);
  vrepack<<<1024, 256, 0, stream>>>(qkv, vp);
  attn<<<1024, 256, 0, stream>>>(qh, kp, vp, Opart, Lbuf);
  combine<<<8192, 256, 0, stream>>>(Opart, Lbuf, yb);
  gemm_bt<<<dim3(8, 32), 256, 0, stream>>>(yb, wpb, (float*)d_out, 1024);
}